// Round 13
// baseline (394.412 us; speedup 1.0000x reference)
//
#include <hip/hip_runtime.h>

#define NROW 6
#define NCOL 6
#define BATCH 1024
#define NSITE 36

// LDS bank-conflict swizzle: XOR dword-addr bits [4:2] with bits [7:5].
// Preserves bits [1:0]; constant within any aligned 4-dword window, so
// float4 accesses stay contiguous/aligned; SWZ(0)==0.
__device__ __forceinline__ int SWZ(int a) { return a ^ (((a >> 5) & 7) << 2); }

// Wave-uniform scalar-memory pointer: address_space(4) = AMDGPU constant.
// Scalar float loads at uniform literal offsets merge into s_load_dwordx4/x16:
// ONE SMEM fetch per wave (R12 proved this: 534 -> 372 us).
typedef const float __attribute__((address_space(4))) * fcp;

// Pre-transpose T[site][spin][u=x][r=gp][d=z][l=g] into
// Tm[(site*2+spin)*256 + (gp*4+z)*16 + (g*4+x)]  (73,728 B in d_ws).
__global__ void peps_reorder_kernel(const float* __restrict__ T,
                                    float* __restrict__ Tm)
{
    int idx = blockIdx.x * 256 + threadIdx.x;   // [0, 18432)
    if (idx >= NSITE * 2 * 256) return;
    int i  = idx & 15;          // i = g*4 + x
    int o  = (idx >> 4) & 15;   // o = gp*4 + z
    int sp = (idx >> 8) & 1;
    int st = idx >> 9;
    int g = i >> 2, x = i & 3, gp = o >> 2, z = o & 3;
    Tm[idx] = T[st * 512 + sp * 256 + x * 64 + gp * 16 + z * 4 + g];
}

// Fixed-slot in-place contraction (verified R8..R12 algebra): state index =
// g*4096 + sum_j slot_j*4^j; step (row,c) reads up-bond x from slot c and
// writes down-bond z back into slot c. ONE barrier/step. State in LDS (64 KB,
// swizzled). M via AS(4) s_load.
// R12 binder analysis: ~165 us of stall at 16 waves/CU (LDS caps us at 2
// blocks/CU). Fix: 1024-thread blocks -> 2 blocks x 16 waves = 32 waves/CU
// (100% occupancy), one spectator per thread. __launch_bounds__(1024,8)
// caps VGPR at 64 (needed for 8 waves/EU); est. usage ~40 -> no spill.
__global__ __launch_bounds__(1024, 8)
void peps_amp_kernel(const int* __restrict__ X, const float* __restrict__ Tm,
                     float* __restrict__ out)
{
    __shared__ float W[16384];   // 65536 B exactly (4^7 fixed-slot state)

    const int b = blockIdx.x;
    const int t = threadIdx.x;   // == this thread's spectator index m
    const int* xrow = X + b * NSITE;

    // PHYS=2: pack the 36 spins into one scalar 64-bit mask (SGPR-resident
    // so every Tm address below is provably wave-uniform).
    unsigned long long sm = 0ull;
    const int4* xp = (const int4*)xrow;
    #pragma unroll
    for (int k = 0; k < 9; ++k) {
        int4 v = xp[k];
        sm |= ((unsigned long long)(v.x & 1)) << (4 * k + 0);
        sm |= ((unsigned long long)(v.y & 1)) << (4 * k + 1);
        sm |= ((unsigned long long)(v.z & 1)) << (4 * k + 2);
        sm |= ((unsigned long long)(v.w & 1)) << (4 * k + 3);
    }
    {
        unsigned lo = __builtin_amdgcn_readfirstlane((int)(sm & 0xffffffffull));
        unsigned hi = __builtin_amdgcn_readfirstlane((int)(sm >> 32));
        sm = ((unsigned long long)hi << 32) | lo;
    }

    if (t == 0) W[0] = 1.0f;     // seed (SWZ(0)==0); covered by step-0 barrier

    int step = 0;
    for (int row = 0; row < NROW; ++row) {
        const int xs = (row == 0) ? 1 : 4;          // up-bond size
        const int zs = (row == NROW - 1) ? 1 : 4;   // down-bond size
        for (int c = 0; c < NCOL; ++c, ++step) {
            const int gin  = (c == 0) ? 1 : 4;
            const int gout = (c == NCOL - 1) ? 1 : 4;
            const int lowb  = (zs == 4) ? 2 * c : 0;
            const int highb = (xs == 4) ? 2 * (5 - c) : 0;
            const int scount = 1 << (lowb + highb);
            const int p4c = 1 << (2 * c);
            const int lowmask = (1 << lowb) - 1;
            const int mr0 = ((t >> lowb) << (2 * c + 2)) | (t & lowmask);
            const bool act = (t < scount);

            // uniform scalar: spin bit + M base for this step (SMEM pointer)
            const int spin = (int)((sm >> step) & 1ull);
            const fcp Msf = (fcp)(unsigned long long)
                (const void*)(Tm + (size_t)(step * 2 + spin) * 256);

            __syncthreads();     // the ONLY barrier per step

            // ---- read phase (divergent, thread-private addresses) ----
            float in[16];
            if (act) {
                if (c == 0) {
                    // x is the low digit -> b128 per g (garbage lanes x>=xs
                    // are simply unused in the FMA)
                    #pragma unroll
                    for (int g = 0; g < 4; ++g) if (g < gin) {
                        float4 r0 = *(const float4*)&W[SWZ(g * 4096 + 4 * t)];
                        in[g*4+0]=r0.x; in[g*4+1]=r0.y;
                        in[g*4+2]=r0.z; in[g*4+3]=r0.w;
                    }
                } else {
                    #pragma unroll
                    for (int g = 0; g < 4; ++g) if (g < gin) {
                        #pragma unroll
                        for (int x = 0; x < 4; ++x) if (x < xs) {
                            in[g*4+x] = W[SWZ(g * 4096 + x * p4c + mr0)];
                        }
                    }
                }
            }

            // ---- compute + write; M via s_load (uniform, invariant) ----
            #pragma unroll
            for (int gp = 0; gp < 4; ++gp) if (gp < gout) {
                float a[4];
                #pragma unroll
                for (int z = 0; z < 4; ++z) if (z < zs) {
                    const int mb = (gp * 4 + z) * 16;
                    float mm[16];
                    #pragma unroll
                    for (int j = 0; j < 4; ++j) mm[j] = Msf[mb + j];
                    if (gin == 4) {
                        #pragma unroll
                        for (int j = 4; j < 16; ++j) mm[j] = Msf[mb + j];
                    }
                    float s0 = 0.f;
                    if (act) {
                        #pragma unroll
                        for (int g = 0; g < 4; ++g) if (g < gin) {
                            s0 += mm[g*4+0] * in[g*4+0];
                            if (xs == 4) {
                                s0 += mm[g*4+1] * in[g*4+1];
                                s0 += mm[g*4+2] * in[g*4+2];
                                s0 += mm[g*4+3] * in[g*4+3];
                            }
                        }
                    }
                    a[z] = s0;
                    if (act) {
                        if (c != 0 && zs == 4) {
                            W[SWZ(gp * 4096 + z * p4c + mr0)] = s0;
                        } else if (zs == 1) {
                            W[SWZ(gp * 4096 + mr0)] = s0;
                        }
                    }
                }
                if (c == 0 && zs == 4 && act) {
                    *(float4*)&W[SWZ(gp * 4096 + 4 * t)] =
                        make_float4(a[0], a[1], a[2], a[3]);
                }
            }
        }
    }
    __syncthreads();
    // after (5,5): only g'=0, z=0, m=0 live -> the amplitude sits at W[0]
    if (t == 0) out[b] = W[0];
}

extern "C" void kernel_launch(void* const* d_in, const int* in_sizes, int n_in,
                              void* d_out, int out_size, void* d_ws, size_t ws_size,
                              hipStream_t stream) {
    const int*   X  = (const int*)d_in[0];     // x: [1024, 36] int32
    const float* Tg = (const float*)d_in[1];   // T: [6,6,2,4,4,4,4] fp32
    float* out = (float*)d_out;                // reference output: float32
    float* Tm  = (float*)d_ws;                 // 73,728 B scratch
    (void)in_sizes; (void)n_in; (void)ws_size; (void)out_size;
    peps_reorder_kernel<<<dim3(72), dim3(256), 0, stream>>>(Tg, Tm);
    peps_amp_kernel<<<dim3(BATCH), dim3(1024), 0, stream>>>(X, Tm, out);
}